// Round 1
// baseline (1197.031 us; speedup 1.0000x reference)
//
#include <hip/hip_runtime.h>
#include <math.h>

#define N_NODES 65536
#define NUM_EDGES 524288
#define E_TOT   (NUM_EDGES + N_NODES)   /* 589824 incl self-loops */
#define GSZ 512

// ---------------- CSR build ----------------
__global__ void k_zero_int(int* __restrict__ p, int n) {
  int i = blockIdx.x * blockDim.x + threadIdx.x;
  if (i < n) p[i] = 0;
}

__global__ void k_hist(const int* __restrict__ ei, int* __restrict__ cnt) {
  int e = blockIdx.x * blockDim.x + threadIdx.x;
  if (e >= E_TOT) return;
  int dst = (e < NUM_EDGES) ? ei[NUM_EDGES + e] : (e - NUM_EDGES);
  atomicAdd(&cnt[dst], 1);
}

__global__ void k_scan1(const int* __restrict__ cnt, int* __restrict__ offs,
                        int* __restrict__ sums) {
  __shared__ int s[256];
  int t = threadIdx.x;
  int i = blockIdx.x * 256 + t;
  int v = cnt[i];
  s[t] = v;
  for (int o = 1; o < 256; o <<= 1) {
    __syncthreads();
    int x = (t >= o) ? s[t - o] : 0;
    __syncthreads();
    s[t] += x;
  }
  offs[i] = s[t] - v;                 // exclusive within block
  if (t == 255) sums[blockIdx.x] = s[t];
}

__global__ void k_scan2(int* __restrict__ sums) {
  __shared__ int s[256];
  int t = threadIdx.x;
  int v = sums[t];
  s[t] = v;
  for (int o = 1; o < 256; o <<= 1) {
    __syncthreads();
    int x = (t >= o) ? s[t - o] : 0;
    __syncthreads();
    s[t] += x;
  }
  sums[t] = s[t] - v;                 // exclusive block offsets
}

__global__ void k_scan3(int* __restrict__ offs, const int* __restrict__ sums,
                        int* __restrict__ cur) {
  int i = blockIdx.x * 256 + threadIdx.x;
  int v = offs[i] + sums[blockIdx.x];
  offs[i] = v;
  cur[i] = v;
  if (i == 0) offs[N_NODES] = E_TOT;
}

__global__ void k_fill(const int* __restrict__ ei, int* __restrict__ cur,
                       int* __restrict__ ssrc) {
  int e = blockIdx.x * blockDim.x + threadIdx.x;
  if (e >= E_TOT) return;
  int src, dst;
  if (e < NUM_EDGES) { src = ei[e]; dst = ei[NUM_EDGES + e]; }
  else               { src = e - NUM_EDGES; dst = src; }
  int pos = atomicAdd(&cur[dst], 1);
  ssrc[pos] = src;
}

// ---------------- fp32 GEMM: C[M,N] = A[M,K] @ B[K,N] (+bias) ----------------
// BM=128 BN=64 BK=16, 256 threads, 8x4 per-thread tile.
__global__ __launch_bounds__(256) void k_gemm(
    const float* __restrict__ A, const float* __restrict__ B,
    const float* __restrict__ bias, float* __restrict__ C,
    int M, int N, int K) {
  __shared__ float As[16][132];   // [k][m], stride 132 (528B, 16B-aligned)
  __shared__ float Bs[16][68];    // [k][n], stride 68 (272B, 16B-aligned)
  int t = threadIdx.x;
  int tx = t & 15, ty = t >> 4;
  int m0 = blockIdx.x * 128, n0 = blockIdx.y * 64;
  float acc[8][4];
#pragma unroll
  for (int i = 0; i < 8; ++i)
#pragma unroll
    for (int j = 0; j < 4; ++j) acc[i][j] = 0.f;

  int lr = t >> 2;              // 0..63
  int lc = (t & 3) << 2;        // 0,4,8,12
  const float* Ab = A + (size_t)m0 * K;

  for (int k0 = 0; k0 < K; k0 += 16) {
    float4 a0 = *(const float4*)&Ab[(size_t)lr * K + k0 + lc];
    float4 a1 = *(const float4*)&Ab[(size_t)(lr + 64) * K + k0 + lc];
    As[lc + 0][lr] = a0.x; As[lc + 1][lr] = a0.y;
    As[lc + 2][lr] = a0.z; As[lc + 3][lr] = a0.w;
    As[lc + 0][lr + 64] = a1.x; As[lc + 1][lr + 64] = a1.y;
    As[lc + 2][lr + 64] = a1.z; As[lc + 3][lr + 64] = a1.w;
    int br = t >> 4, bc = (t & 15) << 2;
    *(float4*)&Bs[br][bc] = *(const float4*)&B[(size_t)(k0 + br) * N + n0 + bc];
    __syncthreads();
#pragma unroll
    for (int kk = 0; kk < 16; ++kk) {
      float a[8], b[4];
      *(float4*)&a[0] = *(float4*)&As[kk][ty * 8];
      *(float4*)&a[4] = *(float4*)&As[kk][ty * 8 + 4];
      *(float4*)&b[0] = *(float4*)&Bs[kk][tx * 4];
#pragma unroll
      for (int i = 0; i < 8; ++i)
#pragma unroll
        for (int j = 0; j < 4; ++j) acc[i][j] += a[i] * b[j];
    }
    __syncthreads();
  }

  float4 bv = make_float4(0.f, 0.f, 0.f, 0.f);
  if (bias) bv = *(const float4*)&bias[n0 + tx * 4];
#pragma unroll
  for (int i = 0; i < 8; ++i) {
    int row = m0 + ty * 8 + i;
    float4 o;
    o.x = acc[i][0] + bv.x; o.y = acc[i][1] + bv.y;
    o.z = acc[i][2] + bv.z; o.w = acc[i][3] + bv.w;
    *(float4*)&C[(size_t)row * N + n0 + tx * 4] = o;
  }
}

// ---------------- per-(node,head) attention scores e_s, e_d ----------------
__global__ void k_scores(const float* __restrict__ h, const float* __restrict__ as_,
                         const float* __restrict__ ad_, float* __restrict__ es,
                         float* __restrict__ ed, int H, int C) {
  int t = blockIdx.x * blockDim.x + threadIdx.x;
  if (t >= N_NODES * H) return;
  int hd = t % H;
  const float* hp = h + (size_t)t * C;        // h[n][hd][:] contiguous
  const float* ap = as_ + hd * C;
  const float* dp = ad_ + hd * C;
  float s = 0.f, d = 0.f;
  for (int c = 0; c < C; c += 4) {
    float4 hv = *(const float4*)&hp[c];
    float4 av = *(const float4*)&ap[c];
    float4 dv = *(const float4*)&dp[c];
    s += hv.x * av.x + hv.y * av.y + hv.z * av.z + hv.w * av.w;
    d += hv.x * dv.x + hv.y * dv.y + hv.z * dv.z + hv.w * dv.w;
  }
  es[t] = s; ed[t] = d;
}

__device__ __forceinline__ float lrelu02(float e) { return e >= 0.f ? e : 0.2f * e; }

// ---------------- GAT aggregate (H=4,C=64) + bias + ELU + LayerNorm ----------------
// one wave per node; lane owns 4 channels; head = lane>>4
__global__ __launch_bounds__(256) void k_agg256(
    const float* __restrict__ h, const float* __restrict__ es,
    const float* __restrict__ ed, const int* __restrict__ offs,
    const int* __restrict__ ssrc, const float* __restrict__ bias,
    const float* __restrict__ lng, const float* __restrict__ lnb,
    float* __restrict__ out) {
  int lane = threadIdx.x & 63;
  int n = blockIdx.x * 4 + (threadIdx.x >> 6);
  int head = lane >> 4;
  int o0 = offs[n], deg = offs[n + 1] - o0;
  float4 edv = *(const float4*)&ed[n * 4];
  float edh = (head & 2) ? ((head & 1) ? edv.w : edv.z)
                         : ((head & 1) ? edv.y : edv.x);
  // pass 1: per-head segment max
  float m0 = -1e30f, m1 = -1e30f, m2 = -1e30f, m3 = -1e30f;
  for (int j = lane; j < deg; j += 64) {
    int s = ssrc[o0 + j];
    float4 ev = *(const float4*)&es[s * 4];
    m0 = fmaxf(m0, lrelu02(ev.x + edv.x));
    m1 = fmaxf(m1, lrelu02(ev.y + edv.y));
    m2 = fmaxf(m2, lrelu02(ev.z + edv.z));
    m3 = fmaxf(m3, lrelu02(ev.w + edv.w));
  }
#pragma unroll
  for (int o = 1; o < 64; o <<= 1) {
    m0 = fmaxf(m0, __shfl_xor(m0, o));
    m1 = fmaxf(m1, __shfl_xor(m1, o));
    m2 = fmaxf(m2, __shfl_xor(m2, o));
    m3 = fmaxf(m3, __shfl_xor(m3, o));
  }
  float mh = (head & 2) ? ((head & 1) ? m3 : m2) : ((head & 1) ? m1 : m0);
  // pass 2: unnormalized weighted sum (edge-serial, lanes own channels)
  float z = 0.f, a0 = 0.f, a1 = 0.f, a2 = 0.f, a3 = 0.f;
  int c0 = lane * 4;
  for (int j = 0; j < deg; ++j) {
    int s = ssrc[o0 + j];
    float p = __expf(lrelu02(es[s * 4 + head] + edh) - mh);
    z += p;
    float4 hv = *(const float4*)&h[(size_t)s * 256 + c0];
    a0 += p * hv.x; a1 += p * hv.y; a2 += p * hv.z; a3 += p * hv.w;
  }
  float inv = 1.f / (z + 1e-16f);
  float4 bv = *(const float4*)&bias[c0];
  float v0 = a0 * inv + bv.x; v0 = v0 > 0.f ? v0 : __expf(v0) - 1.f;
  float v1 = a1 * inv + bv.y; v1 = v1 > 0.f ? v1 : __expf(v1) - 1.f;
  float v2 = a2 * inv + bv.z; v2 = v2 > 0.f ? v2 : __expf(v2) - 1.f;
  float v3 = a3 * inv + bv.w; v3 = v3 > 0.f ? v3 : __expf(v3) - 1.f;
  // LayerNorm over 256 channels (wave reduce)
  float sum = v0 + v1 + v2 + v3;
#pragma unroll
  for (int o = 1; o < 64; o <<= 1) sum += __shfl_xor(sum, o);
  float mean = sum * (1.f / 256.f);
  float d0 = v0 - mean, d1 = v1 - mean, d2 = v2 - mean, d3 = v3 - mean;
  float sq = d0 * d0 + d1 * d1 + d2 * d2 + d3 * d3;
#pragma unroll
  for (int o = 1; o < 64; o <<= 1) sq += __shfl_xor(sq, o);
  float rs = rsqrtf(sq * (1.f / 256.f) + 1e-5f);
  float4 gv = *(const float4*)&lng[c0];
  float4 ev2 = *(const float4*)&lnb[c0];
  float4 o4;
  o4.x = d0 * rs * gv.x + ev2.x; o4.y = d1 * rs * gv.y + ev2.y;
  o4.z = d2 * rs * gv.z + ev2.z; o4.w = d3 * rs * gv.w + ev2.w;
  *(float4*)&out[(size_t)n * 256 + c0] = o4;
}

// ---------------- GAT layer 3 (H=1,C=128) + bias + residual (in-place io) ----------------
__global__ __launch_bounds__(256) void k_agg128(
    const float* __restrict__ h, const float* __restrict__ es,
    const float* __restrict__ ed, const int* __restrict__ offs,
    const int* __restrict__ ssrc, const float* __restrict__ bias,
    float* __restrict__ io) {
  int lane = threadIdx.x & 63;
  int n = blockIdx.x * 4 + (threadIdx.x >> 6);
  int o0 = offs[n], deg = offs[n + 1] - o0;
  float edv = ed[n];
  float mx = -1e30f;
  for (int j = lane; j < deg; j += 64) {
    int s = ssrc[o0 + j];
    mx = fmaxf(mx, lrelu02(es[s] + edv));
  }
#pragma unroll
  for (int o = 1; o < 64; o <<= 1) mx = fmaxf(mx, __shfl_xor(mx, o));
  float z = 0.f, a0 = 0.f, a1 = 0.f;
  int c0 = lane * 2;
  for (int j = 0; j < deg; ++j) {
    int s = ssrc[o0 + j];
    float p = __expf(lrelu02(es[s] + edv) - mx);
    z += p;
    float2 hv = *(const float2*)&h[(size_t)s * 128 + c0];
    a0 += p * hv.x; a1 += p * hv.y;
  }
  float inv = 1.f / (z + 1e-16f);
  float2 r = *(const float2*)&io[(size_t)n * 128 + c0];
  float2 o2;
  o2.x = a0 * inv + bias[c0]     + r.x;
  o2.y = a1 * inv + bias[c0 + 1] + r.y;
  *(float2*)&io[(size_t)n * 128 + c0] = o2;
}

// ---------------- per-graph MHA (flash-style, fp32) ----------------
// block = (graph, head); 256 threads * 2 queries = 512 queries; K/V tiled via LDS
__global__ __launch_bounds__(256) void k_attn(
    const float* __restrict__ Q, const float* __restrict__ K,
    const float* __restrict__ V, float* __restrict__ O) {
  __shared__ float Ks[64][36];
  __shared__ float Vs[64][36];
  int g = blockIdx.x >> 2, hd = blockIdx.x & 3;
  int t = threadIdx.x;
  size_t base = (size_t)g * GSZ * 128 + hd * 32;
  float qa[32], qb[32], aca[32], acb[32];
#pragma unroll
  for (int d = 0; d < 32; d += 4) {
    *(float4*)&qa[d] = *(const float4*)&Q[base + (size_t)t * 128 + d];
    *(float4*)&qb[d] = *(const float4*)&Q[base + (size_t)(t + 256) * 128 + d];
  }
#pragma unroll
  for (int d = 0; d < 32; ++d) { aca[d] = 0.f; acb[d] = 0.f; }
  float ma = -1e30f, mb = -1e30f, la = 0.f, lb = 0.f;
  const float scale = 0.0883883476483184f;   // 1/sqrt(128)

  for (int kt = 0; kt < GSZ; kt += 64) {
    int r = t >> 2, c = (t & 3) << 3;
    const float* kp = &K[base + (size_t)(kt + r) * 128 + c];
    const float* vp = &V[base + (size_t)(kt + r) * 128 + c];
    *(float4*)&Ks[r][c]     = *(const float4*)kp;
    *(float4*)&Ks[r][c + 4] = *(const float4*)(kp + 4);
    *(float4*)&Vs[r][c]     = *(const float4*)vp;
    *(float4*)&Vs[r][c + 4] = *(const float4*)(vp + 4);
    __syncthreads();
    for (int kk = 0; kk < 64; ++kk) {
      float ea = 0.f, eb = 0.f;
#pragma unroll
      for (int d = 0; d < 32; d += 4) {
        float4 kv = *(float4*)&Ks[kk][d];
        ea += qa[d] * kv.x + qa[d + 1] * kv.y + qa[d + 2] * kv.z + qa[d + 3] * kv.w;
        eb += qb[d] * kv.x + qb[d + 1] * kv.y + qb[d + 2] * kv.z + qb[d + 3] * kv.w;
      }
      ea *= scale; eb *= scale;
      if (ea > ma) {
        float c_ = __expf(ma - ea); la *= c_;
#pragma unroll
        for (int d = 0; d < 32; ++d) aca[d] *= c_;
        ma = ea;
      }
      float pa = __expf(ea - ma); la += pa;
      if (eb > mb) {
        float c_ = __expf(mb - eb); lb *= c_;
#pragma unroll
        for (int d = 0; d < 32; ++d) acb[d] *= c_;
        mb = eb;
      }
      float pb = __expf(eb - mb); lb += pb;
#pragma unroll
      for (int d = 0; d < 32; d += 4) {
        float4 vv = *(float4*)&Vs[kk][d];
        aca[d] += pa * vv.x; aca[d + 1] += pa * vv.y;
        aca[d + 2] += pa * vv.z; aca[d + 3] += pa * vv.w;
        acb[d] += pb * vv.x; acb[d + 1] += pb * vv.y;
        acb[d + 2] += pb * vv.z; acb[d + 3] += pb * vv.w;
      }
    }
    __syncthreads();
  }
  float ia = 1.f / la, ib = 1.f / lb;
#pragma unroll
  for (int d = 0; d < 32; d += 4) {
    float4 oa, ob;
    oa.x = aca[d] * ia; oa.y = aca[d + 1] * ia;
    oa.z = aca[d + 2] * ia; oa.w = aca[d + 3] * ia;
    ob.x = acb[d] * ib; ob.y = acb[d + 1] * ib;
    ob.z = acb[d + 2] * ib; ob.w = acb[d + 3] * ib;
    *(float4*)&O[base + (size_t)t * 128 + d] = oa;
    *(float4*)&O[base + (size_t)(t + 256) * 128 + d] = ob;
  }
}

// ---------------- launch ----------------
extern "C" void kernel_launch(void* const* d_in, const int* in_sizes, int n_in,
                              void* d_out, int out_size, void* d_ws, size_t ws_size,
                              hipStream_t stream) {
  (void)in_sizes; (void)n_in; (void)out_size; (void)ws_size;
  const float* x   = (const float*)d_in[0];
  const int*   ei  = (const int*)d_in[1];
  const float* W1  = (const float*)d_in[3];
  const float* a1s = (const float*)d_in[4];
  const float* a1d = (const float*)d_in[5];
  const float* b1  = (const float*)d_in[6];
  const float* W2  = (const float*)d_in[7];
  const float* a2s = (const float*)d_in[8];
  const float* a2d = (const float*)d_in[9];
  const float* b2  = (const float*)d_in[10];
  const float* W3  = (const float*)d_in[11];
  const float* a3s = (const float*)d_in[12];
  const float* a3d = (const float*)d_in[13];
  const float* b3  = (const float*)d_in[14];
  const float* g1  = (const float*)d_in[15];
  const float* be1 = (const float*)d_in[16];
  const float* g2  = (const float*)d_in[17];
  const float* be2 = (const float*)d_in[18];
  const float* Wr  = (const float*)d_in[19];
  const float* br  = (const float*)d_in[20];
  const float* Wq  = (const float*)d_in[21];
  const float* Wk  = (const float*)d_in[22];
  const float* Wv  = (const float*)d_in[23];
  const float* Wo  = (const float*)d_in[24];
  const float* bo  = (const float*)d_in[25];
  float* out = (float*)d_out;

  // workspace layout (~139 MB)
  float* Hbuf = (float*)d_ws;                       // N*256
  float* Abuf = Hbuf + (size_t)N_NODES * 256;       // N*256
  float* esb  = Abuf + (size_t)N_NODES * 256;       // N*4
  float* edb  = esb  + (size_t)N_NODES * 4;         // N*4
  int* offs = (int*)(edb + (size_t)N_NODES * 4);    // N+1
  int* cur  = offs + N_NODES + 4;                   // N
  int* ssrc = cur + N_NODES;                        // E_TOT
  int* sums = ssrc + E_TOT;                         // 256

  dim3 blk(256);
  // CSR build (shared by all 3 GAT layers)
  k_zero_int<<<256, blk, 0, stream>>>(cur, N_NODES);
  k_hist<<<(E_TOT + 255) / 256, blk, 0, stream>>>(ei, cur);
  k_scan1<<<256, blk, 0, stream>>>(cur, offs, sums);
  k_scan2<<<1, blk, 0, stream>>>(sums);
  k_scan3<<<256, blk, 0, stream>>>(offs, sums, cur);
  k_fill<<<(E_TOT + 255) / 256, blk, 0, stream>>>(ei, cur, ssrc);

  dim3 g2d(512, 2), g4d(512, 4);
  // residual r = x @ Wr + br  -> d_out (acts as Rbuf; fully overwritten at the end)
  k_gemm<<<g2d, blk, 0, stream>>>(x, Wr, br, out, N_NODES, 128, 64);

  // ---- GAT layer 1 ----
  k_gemm<<<g4d, blk, 0, stream>>>(x, W1, nullptr, Hbuf, N_NODES, 256, 64);
  k_scores<<<N_NODES * 4 / 256, blk, 0, stream>>>(Hbuf, a1s, a1d, esb, edb, 4, 64);
  k_agg256<<<N_NODES / 4, blk, 0, stream>>>(Hbuf, esb, edb, offs, ssrc, b1, g1, be1, Abuf);
  // ---- GAT layer 2 ----
  k_gemm<<<g4d, blk, 0, stream>>>(Abuf, W2, nullptr, Hbuf, N_NODES, 256, 256);
  k_scores<<<N_NODES * 4 / 256, blk, 0, stream>>>(Hbuf, a2s, a2d, esb, edb, 4, 64);
  k_agg256<<<N_NODES / 4, blk, 0, stream>>>(Hbuf, esb, edb, offs, ssrc, b2, g2, be2, Abuf);
  // ---- GAT layer 3 (+ bias + residual, in-place on d_out) ----
  k_gemm<<<g2d, blk, 0, stream>>>(Abuf, W3, nullptr, Hbuf, N_NODES, 128, 256);
  k_scores<<<N_NODES / 256, blk, 0, stream>>>(Hbuf, a3s, a3d, esb, edb, 1, 128);
  k_agg128<<<N_NODES / 4, blk, 0, stream>>>(Hbuf, esb, edb, offs, ssrc, b3, out);

  // ---- per-graph MHA ----
  float* Qb  = Abuf;
  float* Kb  = Abuf + (size_t)N_NODES * 128;
  float* Vb  = Hbuf;
  float* AOb = Hbuf + (size_t)N_NODES * 128;
  k_gemm<<<g2d, blk, 0, stream>>>(out, Wq, nullptr, Qb, N_NODES, 128, 128);
  k_gemm<<<g2d, blk, 0, stream>>>(out, Wk, nullptr, Kb, N_NODES, 128, 128);
  k_gemm<<<g2d, blk, 0, stream>>>(out, Wv, nullptr, Vb, N_NODES, 128, 128);
  k_attn<<<512, blk, 0, stream>>>(Qb, Kb, Vb, AOb);
  k_gemm<<<g2d, blk, 0, stream>>>(AOb, Wo, bo, out, N_NODES, 128, 128);
}